// Round 1
// baseline (45.757 us; speedup 1.0000x reference)
//
#include <hip/hip_runtime.h>

#define BB 16
#define NN 2048
#define NFF 512
#define DD 4

// ---------------- Kernel 1: elementwise pre-pass ----------------
// X = sigmoid((V - 1 - th)*5)  -> out_X (first half of d_out)
// T[b,i] = sum_d Xd*(1 + 0.95*stp - 0.3*Xd) -> ws
// c1[b] = sum_i T*xpre_int ; c2[b] = sum_i T*Xd0
// c3[b] = sum_i FF*xpre_ff ; c4[b] = sum_i FF*FF   (atomic into scal)
__global__ __launch_bounds__(256) void snn_pre(
    const float* __restrict__ FF, const float* __restrict__ V,
    const float* __restrict__ th, const float* __restrict__ Xbuf,
    const float* __restrict__ stp, const float* __restrict__ xpre_int,
    const float* __restrict__ xpre_ff,
    float* __restrict__ out_X, float* __restrict__ T, float* __restrict__ scal)
{
    int idx = blockIdx.x * 256 + threadIdx.x;
    if (idx < BB * NN) {
        int b = idx >> 11;                       // N = 2048
        float v = V[idx], t = th[idx];
        float x = 1.f / (1.f + expf(-(v - 1.f - t) * 5.f));
        out_X[idx] = x;
        float xd0 = Xbuf[idx];
        float acc = 0.f;
        #pragma unroll
        for (int d = 0; d < DD; ++d) {
            float xd = Xbuf[d * BB * NN + idx];
            float s  = stp[d * BB * NN + idx];
            acc += xd * (1.f + 0.95f * s - 0.3f * xd);
        }
        T[idx] = acc;
        float c1 = acc * xpre_int[idx];
        float c2 = acc * xd0;
        #pragma unroll
        for (int o = 32; o; o >>= 1) { c1 += __shfl_xor(c1, o); c2 += __shfl_xor(c2, o); }
        if ((threadIdx.x & 63) == 0) {
            atomicAdd(&scal[0 * BB + b], c1);
            atomicAdd(&scal[1 * BB + b], c2);
        }
    } else {
        int k = idx - BB * NN;                   // < B*NFF, block-uniform branch
        int b = k >> 9;                          // NFF = 512
        float f = FF[k];
        float c3 = f * xpre_ff[k];
        float c4 = f * f;
        #pragma unroll
        for (int o = 32; o; o >>= 1) { c3 += __shfl_xor(c3, o); c4 += __shfl_xor(c4, o); }
        if ((threadIdx.x & 63) == 0) {
            atomicAdd(&scal[2 * BB + b], c3);
            atomicAdd(&scal[3 * BB + b], c4);
        }
    }
}

// ---------------- Kernel 2: batched GEMV (the heavy one) ----------------
// cur[b,j] += sum_i OP[b,i] * W[i,j], K split across blockIdx.y.
// y in [0,64):   W_int rows  [y*32, y*32+32),   OP = T   (stride N)
// y in [64,80):  W_ff  rows  [(y-64)*32, ...),  OP = FF  (stride NFF)
#define RROWS 32
#define RJ 512
__global__ __launch_bounds__(256) void snn_gemv(
    const float* __restrict__ Wint, const float* __restrict__ Wff,
    const float* __restrict__ T, const float* __restrict__ FF,
    float* __restrict__ cur)
{
    __shared__ float op_lds[RROWS * BB];         // [ii][b], transposed
    int y = blockIdx.y;
    const float* Wm; const float* OP; int i0, opstride;
    if (y < 64) { Wm = Wint; OP = T;  i0 = y * RROWS;        opstride = NN;  }
    else        { Wm = Wff;  OP = FF; i0 = (y - 64) * RROWS; opstride = NFF; }

    int t = threadIdx.x;
    for (int e = t; e < RROWS * BB; e += 256) {
        int ii = e >> 4, b = e & 15;
        op_lds[e] = OP[b * opstride + i0 + ii];
    }
    __syncthreads();

    int j0 = blockIdx.x * RJ + t * 2;
    float2 acc[BB];
    #pragma unroll
    for (int b = 0; b < BB; ++b) acc[b] = make_float2(0.f, 0.f);

    const float* wp = &Wm[(size_t)i0 * NN + j0]; // both W have row length N
    #pragma unroll 4
    for (int ii = 0; ii < RROWS; ++ii) {
        float2 w = *(const float2*)wp; wp += NN;
        const float4* tl = (const float4*)&op_lds[ii * 16];
        float4 t0 = tl[0], t1 = tl[1], t2 = tl[2], t3 = tl[3];
#define FMA4(tq, base) \
        acc[base+0].x += tq.x * w.x; acc[base+0].y += tq.x * w.y; \
        acc[base+1].x += tq.y * w.x; acc[base+1].y += tq.y * w.y; \
        acc[base+2].x += tq.z * w.x; acc[base+2].y += tq.z * w.y; \
        acc[base+3].x += tq.w * w.x; acc[base+3].y += tq.w * w.y;
        FMA4(t0, 0) FMA4(t1, 4) FMA4(t2, 8) FMA4(t3, 12)
#undef FMA4
    }

    #pragma unroll
    for (int b = 0; b < BB; ++b) {
        atomicAdd(&cur[b * NN + j0],     acc[b].x);
        atomicAdd(&cur[b * NN + j0 + 1], acc[b].y);
    }
}

// ---------------- Kernel 3: finalize ----------------
// current = cur + A_P*(c1+c3)*X - A_D*(c2+c4)*xpost ; V_new = 0.9*V*(1-X)+current
__global__ __launch_bounds__(256) void snn_post(
    const float* __restrict__ V, const float* __restrict__ xpost,
    const float* __restrict__ cur, const float* __restrict__ scal,
    const float* __restrict__ out_X, float* __restrict__ out_V)
{
    int idx = blockIdx.x * 256 + threadIdx.x;
    int b = idx >> 11;
    float x = out_X[idx];
    float c = cur[idx] + 0.01f  * (scal[0 * BB + b] + scal[2 * BB + b]) * x
                       - 0.012f * (scal[1 * BB + b] + scal[3 * BB + b]) * xpost[idx];
    out_V[idx] = 0.9f * V[idx] * (1.f - x) + c;
}

extern "C" void kernel_launch(void* const* d_in, const int* in_sizes, int n_in,
                              void* d_out, int out_size, void* d_ws, size_t ws_size,
                              hipStream_t stream) {
    const float* FF       = (const float*)d_in[0];
    const float* V        = (const float*)d_in[1];
    const float* th       = (const float*)d_in[2];
    const float* Xbuf     = (const float*)d_in[3];
    const float* stp      = (const float*)d_in[4];
    const float* xpre_int = (const float*)d_in[5];
    const float* xpost    = (const float*)d_in[6];
    const float* xpre_ff  = (const float*)d_in[7];
    const float* Wint     = (const float*)d_in[8];
    const float* Wff      = (const float*)d_in[9];
    float* out = (float*)d_out;
    float* ws  = (float*)d_ws;

    float* T    = ws;                  // B*N floats
    float* cur  = ws + BB * NN;        // B*N floats (atomic accumulator)
    float* scal = ws + 2 * BB * NN;    // 4*B floats

    // zero the atomic accumulators (cur + scal) each call
    hipMemsetAsync(cur, 0, (BB * NN + 4 * BB) * sizeof(float), stream);

    snn_pre<<<(BB * NN + BB * NFF) / 256, 256, 0, stream>>>(
        FF, V, th, Xbuf, stp, xpre_int, xpre_ff, out, T, scal);

    snn_gemv<<<dim3(NN / RJ, 64 + NFF / RROWS), 256, 0, stream>>>(
        Wint, Wff, T, FF, cur);

    snn_post<<<BB * NN / 256, 256, 0, stream>>>(
        V, xpost, cur, scal, out, out + BB * NN);
}

// Round 2
// 35.118 us; speedup vs baseline: 1.3030x; 1.3030x over previous
//
#include <hip/hip_runtime.h>

#define BB 16
#define NN 2048
#define NFF 512
#define DD 4

// ---------------- Kernel 1: elementwise pre-pass ----------------
// X = sigmoid((V - 1 - th)*5)  -> out_X (first half of d_out)
// T[b,i] = sum_d Xd*(1 + 0.95*stp - 0.3*Xd) -> ws
// Also zeroes the gemv atomic accumulator `cur` (no memset node needed),
// and writes per-block partial sums for the 4 per-batch scalars:
//   blocks [0,128):  p0 = sum T*xpre_int, p1 = sum T*Xd0      (8 blocks / batch)
//   blocks [128,160): p0 = sum FF*xpre_ff, p1 = sum FF*FF     (2 blocks / batch)
__global__ __launch_bounds__(256) void snn_pre(
    const float* __restrict__ FF, const float* __restrict__ V,
    const float* __restrict__ th, const float* __restrict__ Xbuf,
    const float* __restrict__ stp, const float* __restrict__ xpre_int,
    const float* __restrict__ xpre_ff,
    float* __restrict__ out_X, float* __restrict__ T,
    float* __restrict__ cur, float* __restrict__ scal_part)
{
    __shared__ float red[8];                     // 4 waves x 2 partials
    int idx = blockIdx.x * 256 + threadIdx.x;
    float p0, p1;
    if (idx < BB * NN) {
        float v = V[idx], t = th[idx];
        float x = 1.f / (1.f + expf(-(v - 1.f - t) * 5.f));
        out_X[idx] = x;
        cur[idx] = 0.f;                          // zero gemv accumulator
        float xd0 = Xbuf[idx];
        float acc = 0.f;
        #pragma unroll
        for (int d = 0; d < DD; ++d) {
            float xd = Xbuf[d * BB * NN + idx];
            float s  = stp[d * BB * NN + idx];
            acc += xd * (1.f + 0.95f * s - 0.3f * xd);
        }
        T[idx] = acc;
        p0 = acc * xpre_int[idx];
        p1 = acc * xd0;
    } else {
        int k = idx - BB * NN;                   // < B*NFF, block-uniform branch
        float f = FF[k];
        p0 = f * xpre_ff[k];
        p1 = f * f;
    }
    #pragma unroll
    for (int o = 32; o; o >>= 1) { p0 += __shfl_xor(p0, o); p1 += __shfl_xor(p1, o); }
    int w = threadIdx.x >> 6;
    if ((threadIdx.x & 63) == 0) { red[w * 2] = p0; red[w * 2 + 1] = p1; }
    __syncthreads();
    if (threadIdx.x == 0) {
        scal_part[blockIdx.x * 2]     = red[0] + red[2] + red[4] + red[6];
        scal_part[blockIdx.x * 2 + 1] = red[1] + red[3] + red[5] + red[7];
    }
}

// ---------------- Kernel 2: batched GEMV (the heavy one) ----------------
// cur[b,j] += sum_i OP[b,i] * W[i,j], K split across blockIdx.y.
// y in [0,64):   W_int rows  [y*32, y*32+32),   OP = T   (stride N)
// y in [64,80):  W_ff  rows  [(y-64)*32, ...),  OP = FF  (stride NFF)
#define RROWS 32
#define RJ 512
__global__ __launch_bounds__(256) void snn_gemv(
    const float* __restrict__ Wint, const float* __restrict__ Wff,
    const float* __restrict__ T, const float* __restrict__ FF,
    float* __restrict__ cur)
{
    __shared__ float op_lds[RROWS * BB];         // [ii][b], transposed
    int y = blockIdx.y;
    const float* Wm; const float* OP; int i0, opstride;
    if (y < 64) { Wm = Wint; OP = T;  i0 = y * RROWS;        opstride = NN;  }
    else        { Wm = Wff;  OP = FF; i0 = (y - 64) * RROWS; opstride = NFF; }

    int t = threadIdx.x;
    for (int e = t; e < RROWS * BB; e += 256) {
        int ii = e >> 4, b = e & 15;
        op_lds[e] = OP[b * opstride + i0 + ii];
    }
    __syncthreads();

    int j0 = blockIdx.x * RJ + t * 2;
    float2 acc[BB];
    #pragma unroll
    for (int b = 0; b < BB; ++b) acc[b] = make_float2(0.f, 0.f);

    const float* wp = &Wm[(size_t)i0 * NN + j0]; // both W have row length N
    #pragma unroll 4
    for (int ii = 0; ii < RROWS; ++ii) {
        float2 w = *(const float2*)wp; wp += NN;
        const float4* tl = (const float4*)&op_lds[ii * 16];
        float4 t0 = tl[0], t1 = tl[1], t2 = tl[2], t3 = tl[3];
#define FMA4(tq, base) \
        acc[base+0].x += tq.x * w.x; acc[base+0].y += tq.x * w.y; \
        acc[base+1].x += tq.y * w.x; acc[base+1].y += tq.y * w.y; \
        acc[base+2].x += tq.z * w.x; acc[base+2].y += tq.z * w.y; \
        acc[base+3].x += tq.w * w.x; acc[base+3].y += tq.w * w.y;
        FMA4(t0, 0) FMA4(t1, 4) FMA4(t2, 8) FMA4(t3, 12)
#undef FMA4
    }

    #pragma unroll
    for (int b = 0; b < BB; ++b) {
        atomicAdd(&cur[b * NN + j0],     acc[b].x);
        atomicAdd(&cur[b * NN + j0 + 1], acc[b].y);
    }
}

// ---------------- Kernel 3: finalize ----------------
// current = cur + A_P*(c1+c3)*X - A_D*(c2+c4)*xpost ; V_new = 0.9*V*(1-X)+current
__global__ __launch_bounds__(256) void snn_post(
    const float* __restrict__ V, const float* __restrict__ xpost,
    const float* __restrict__ cur, const float* __restrict__ scal_part,
    const float* __restrict__ out_X, float* __restrict__ out_V)
{
    int idx = blockIdx.x * 256 + threadIdx.x;
    int b = idx >> 11;                           // block-uniform (8 blocks / batch)
    float c1 = 0.f, c2 = 0.f, c3 = 0.f, c4 = 0.f;
    #pragma unroll
    for (int k = 0; k < 8; ++k) {
        c1 += scal_part[(b * 8 + k) * 2];
        c2 += scal_part[(b * 8 + k) * 2 + 1];
    }
    #pragma unroll
    for (int k = 0; k < 2; ++k) {
        c3 += scal_part[(128 + b * 2 + k) * 2];
        c4 += scal_part[(128 + b * 2 + k) * 2 + 1];
    }
    float x = out_X[idx];
    float c = cur[idx] + 0.01f * (c1 + c3) * x - 0.012f * (c2 + c4) * xpost[idx];
    out_V[idx] = 0.9f * V[idx] * (1.f - x) + c;
}

extern "C" void kernel_launch(void* const* d_in, const int* in_sizes, int n_in,
                              void* d_out, int out_size, void* d_ws, size_t ws_size,
                              hipStream_t stream) {
    const float* FF       = (const float*)d_in[0];
    const float* V        = (const float*)d_in[1];
    const float* th       = (const float*)d_in[2];
    const float* Xbuf     = (const float*)d_in[3];
    const float* stp      = (const float*)d_in[4];
    const float* xpre_int = (const float*)d_in[5];
    const float* xpost    = (const float*)d_in[6];
    const float* xpre_ff  = (const float*)d_in[7];
    const float* Wint     = (const float*)d_in[8];
    const float* Wff      = (const float*)d_in[9];
    float* out = (float*)d_out;
    float* ws  = (float*)d_ws;

    float* T    = ws;                  // B*N floats
    float* cur  = ws + BB * NN;        // B*N floats (atomic accumulator, zeroed by snn_pre)
    float* sp   = ws + 2 * BB * NN;    // 320 floats of per-block partials

    snn_pre<<<(BB * NN + BB * NFF) / 256, 256, 0, stream>>>(
        FF, V, th, Xbuf, stp, xpre_int, xpre_ff, out, T, cur, sp);

    snn_gemv<<<dim3(NN / RJ, 64 + NFF / RROWS), 256, 0, stream>>>(
        Wint, Wff, T, FF, cur);

    snn_post<<<BB * NN / 256, 256, 0, stream>>>(
        V, xpost, cur, sp, out, out + BB * NN);
}

// Round 3
// 25.465 us; speedup vs baseline: 1.7968x; 1.3790x over previous
//
#include <hip/hip_runtime.h>

#define BB 16
#define NN 2048
#define NFF 512
#define DD 4

#define ROWS 64        // K-rows per gemv block
#define YINT 32        // 32*64 = 2048 Wint rows
#define YFF  8         // 8*64 = 512 Wff rows
#define YTOT 40
#define JC   128       // columns per x-block (64 threads x 2 cols)
#define PF   8         // prefetch depth (rows)

// ---------------- Kernel 1: elementwise pre-pass ----------------
// X = sigmoid((V-1-th)*5) -> out_X ; T[b,i] = sum_d Xd*(1+0.95*stp-0.3*Xd) -> ws
// Per-block partial sums for the 4 per-batch scalars:
//   blocks [0,128):   p0 = sum T*xpre_int, p1 = sum T*Xd0   (8 blocks/batch)
//   blocks [128,160): p0 = sum FF*xpre_ff, p1 = sum FF*FF   (2 blocks/batch)
__global__ __launch_bounds__(256) void snn_pre(
    const float* __restrict__ FF, const float* __restrict__ V,
    const float* __restrict__ th, const float* __restrict__ Xbuf,
    const float* __restrict__ stp, const float* __restrict__ xpre_int,
    const float* __restrict__ xpre_ff,
    float* __restrict__ out_X, float* __restrict__ T,
    float* __restrict__ scal_part)
{
    __shared__ float red[8];
    int idx = blockIdx.x * 256 + threadIdx.x;
    float p0, p1;
    if (idx < BB * NN) {
        float v = V[idx], t = th[idx];
        float x = 1.f / (1.f + expf(-(v - 1.f - t) * 5.f));
        out_X[idx] = x;
        float xd0 = Xbuf[idx];
        float acc = 0.f;
        #pragma unroll
        for (int d = 0; d < DD; ++d) {
            float xd = Xbuf[d * BB * NN + idx];
            float s  = stp[d * BB * NN + idx];
            acc += xd * (1.f + 0.95f * s - 0.3f * xd);
        }
        T[idx] = acc;
        p0 = acc * xpre_int[idx];
        p1 = acc * xd0;
    } else {
        int k = idx - BB * NN;
        float f = FF[k];
        p0 = f * xpre_ff[k];
        p1 = f * f;
    }
    #pragma unroll
    for (int o = 32; o; o >>= 1) { p0 += __shfl_xor(p0, o); p1 += __shfl_xor(p1, o); }
    int w = threadIdx.x >> 6;
    if ((threadIdx.x & 63) == 0) { red[w * 2] = p0; red[w * 2 + 1] = p1; }
    __syncthreads();
    if (threadIdx.x == 0) {
        scal_part[blockIdx.x * 2]     = red[0] + red[2] + red[4] + red[6];
        scal_part[blockIdx.x * 2 + 1] = red[1] + red[3] + red[5] + red[7];
    }
}

// ---------------- Kernel 2: split-K batched GEMV, no atomics ----------------
// part[y][b][j] = sum_{i in y's 64 rows} OP[b,i] * W[i,j]
// y in [0,32): Wint / OP=T ; y in [32,40): Wff / OP=FF. 1 wave per block,
// 8-deep double-buffered row prefetch for MLP.
__global__ __launch_bounds__(64) void snn_gemv(
    const float* __restrict__ Wint, const float* __restrict__ Wff,
    const float* __restrict__ T, const float* __restrict__ FF,
    float* __restrict__ part)
{
    __shared__ float c_lds[ROWS * BB];           // [row][b]
    int y = blockIdx.y;
    const float* Wm; const float* OP; int i0, opstride;
    if (y < YINT) { Wm = Wint; OP = T;  i0 = y * ROWS;          opstride = NN;  }
    else          { Wm = Wff;  OP = FF; i0 = (y - YINT) * ROWS; opstride = NFF; }

    int t = threadIdx.x;
    #pragma unroll
    for (int k = 0; k < ROWS * BB / 64; ++k) {
        int e = k * 64 + t;
        int row = e >> 4, b = e & 15;
        c_lds[e] = OP[b * opstride + i0 + row];
    }
    __syncthreads();

    int j0 = blockIdx.x * JC + t * 2;
    float2 acc[BB];
    #pragma unroll
    for (int b = 0; b < BB; ++b) acc[b] = make_float2(0.f, 0.f);

    const float* wp = Wm + (size_t)i0 * NN + j0;
    float2 buf[PF];
    #pragma unroll
    for (int r = 0; r < PF; ++r) buf[r] = *(const float2*)(wp + (size_t)r * NN);

    #pragma unroll
    for (int g = 0; g < ROWS / PF; ++g) {
        float2 nxt[PF];
        if (g + 1 < ROWS / PF) {
            const float* wq = wp + (size_t)(g + 1) * PF * NN;
            #pragma unroll
            for (int r = 0; r < PF; ++r) nxt[r] = *(const float2*)(wq + (size_t)r * NN);
        }
        #pragma unroll
        for (int r = 0; r < PF; ++r) {
            const float4* cb = (const float4*)&c_lds[(g * PF + r) * BB];
            float4 c0 = cb[0], c1 = cb[1], c2 = cb[2], c3 = cb[3];
            float2 w = buf[r];
#define FMA2(b, cc) acc[b].x += (cc) * w.x; acc[b].y += (cc) * w.y;
            FMA2(0,  c0.x) FMA2(1,  c0.y) FMA2(2,  c0.z) FMA2(3,  c0.w)
            FMA2(4,  c1.x) FMA2(5,  c1.y) FMA2(6,  c1.z) FMA2(7,  c1.w)
            FMA2(8,  c2.x) FMA2(9,  c2.y) FMA2(10, c2.z) FMA2(11, c2.w)
            FMA2(12, c3.x) FMA2(13, c3.y) FMA2(14, c3.z) FMA2(15, c3.w)
#undef FMA2
        }
        if (g + 1 < ROWS / PF) {
            #pragma unroll
            for (int r = 0; r < PF; ++r) buf[r] = nxt[r];
        }
    }

    float* pp = part + (size_t)y * (BB * NN) + j0;
    #pragma unroll
    for (int b = 0; b < BB; ++b)
        *(float2*)(pp + (size_t)b * NN) = acc[b];
}

// ---------------- Kernel 3: reduce partials + finalize ----------------
__global__ __launch_bounds__(256) void snn_post(
    const float* __restrict__ V, const float* __restrict__ xpost,
    const float* __restrict__ part, const float* __restrict__ scal_part,
    const float* __restrict__ out_X, float* __restrict__ out_V)
{
    int idx = blockIdx.x * 256 + threadIdx.x;
    int b = idx >> 11;
    float c1 = 0.f, c2 = 0.f, c3 = 0.f, c4 = 0.f;
    #pragma unroll
    for (int k = 0; k < 8; ++k) {
        c1 += scal_part[(b * 8 + k) * 2];
        c2 += scal_part[(b * 8 + k) * 2 + 1];
    }
    #pragma unroll
    for (int k = 0; k < 2; ++k) {
        c3 += scal_part[(128 + b * 2 + k) * 2];
        c4 += scal_part[(128 + b * 2 + k) * 2 + 1];
    }
    float s = 0.f;
    #pragma unroll
    for (int y = 0; y < YTOT; ++y) s += part[(size_t)y * (BB * NN) + idx];
    float x = out_X[idx];
    float c = s + 0.01f * (c1 + c3) * x - 0.012f * (c2 + c4) * xpost[idx];
    out_V[idx] = 0.9f * V[idx] * (1.f - x) + c;
}

extern "C" void kernel_launch(void* const* d_in, const int* in_sizes, int n_in,
                              void* d_out, int out_size, void* d_ws, size_t ws_size,
                              hipStream_t stream) {
    const float* FF       = (const float*)d_in[0];
    const float* V        = (const float*)d_in[1];
    const float* th       = (const float*)d_in[2];
    const float* Xbuf     = (const float*)d_in[3];
    const float* stp      = (const float*)d_in[4];
    const float* xpre_int = (const float*)d_in[5];
    const float* xpost    = (const float*)d_in[6];
    const float* xpre_ff  = (const float*)d_in[7];
    const float* Wint     = (const float*)d_in[8];
    const float* Wff      = (const float*)d_in[9];
    float* out = (float*)d_out;
    float* ws  = (float*)d_ws;

    float* T    = ws;                               // 32768 floats
    float* part = ws + BB * NN;                     // 40 * 32768 floats
    float* sp   = ws + BB * NN + YTOT * BB * NN;    // 320 floats

    snn_pre<<<(BB * NN + BB * NFF) / 256, 256, 0, stream>>>(
        FF, V, th, Xbuf, stp, xpre_int, xpre_ff, out, T, sp);

    snn_gemv<<<dim3(NN / JC, YTOT), 64, 0, stream>>>(
        Wint, Wff, T, FF, part);

    snn_post<<<BB * NN / 256, 256, 0, stream>>>(
        V, xpost, part, sp, out, out + BB * NN);
}

// Round 4
// 21.030 us; speedup vs baseline: 2.1758x; 1.2109x over previous
//
#include <hip/hip_runtime.h>

#define BB 16
#define NN 2048
#define NFF 512
#define DD 4

#define ROWS 64        // K-rows per gemv block (4 waves x 16 rows)
#define WR 16          // rows per wave
#define YINT 32        // 32*64 = 2048 Wint rows
#define YTOT 40        // + 8*64 = 512 Wff rows
#define JC   128       // columns per x-block (64 lanes x 2 cols)

// ---------------- Kernel 1: elementwise pre-pass ----------------
// X = sigmoid((V-1-th)*5) -> out_X ; T[b,i] = sum_d Xd*(1+0.95*stp-0.3*Xd) -> ws
// Per-block partial sums for the 4 per-batch scalars:
//   blocks [0,128):   p0 = sum T*xpre_int, p1 = sum T*Xd0   (8 blocks/batch)
//   blocks [128,160): p0 = sum FF*xpre_ff, p1 = sum FF*FF   (2 blocks/batch)
__global__ __launch_bounds__(256) void snn_pre(
    const float* __restrict__ FF, const float* __restrict__ V,
    const float* __restrict__ th, const float* __restrict__ Xbuf,
    const float* __restrict__ stp, const float* __restrict__ xpre_int,
    const float* __restrict__ xpre_ff,
    float* __restrict__ out_X, float* __restrict__ T,
    float* __restrict__ scal_part)
{
    __shared__ float red[8];
    int idx = blockIdx.x * 256 + threadIdx.x;
    float p0, p1;
    if (idx < BB * NN) {
        float v = V[idx], t = th[idx];
        float x = 1.f / (1.f + expf(-(v - 1.f - t) * 5.f));
        out_X[idx] = x;
        float xd0 = Xbuf[idx];
        float acc = 0.f;
        #pragma unroll
        for (int d = 0; d < DD; ++d) {
            float xd = Xbuf[d * BB * NN + idx];
            float s  = stp[d * BB * NN + idx];
            acc += xd * (1.f + 0.95f * s - 0.3f * xd);
        }
        T[idx] = acc;
        p0 = acc * xpre_int[idx];
        p1 = acc * xd0;
    } else {
        int k = idx - BB * NN;
        float f = FF[k];
        p0 = f * xpre_ff[k];
        p1 = f * f;
    }
    #pragma unroll
    for (int o = 32; o; o >>= 1) { p0 += __shfl_xor(p0, o); p1 += __shfl_xor(p1, o); }
    int w = threadIdx.x >> 6;
    if ((threadIdx.x & 63) == 0) { red[w * 2] = p0; red[w * 2 + 1] = p1; }
    __syncthreads();
    if (threadIdx.x == 0) {
        scal_part[blockIdx.x * 2]     = red[0] + red[2] + red[4] + red[6];
        scal_part[blockIdx.x * 2 + 1] = red[1] + red[3] + red[5] + red[7];
    }
}

// ---------------- Kernel 2: split-K batched GEMV ----------------
// part[y][b][j] = sum_{i in y's 64 rows} OP[b,i] * W[i,j]
// y in [0,32): Wint / OP=T ; y in [32,40): Wff / OP=FF.
// 4 waves/block, 16 rows/wave (16 outstanding loads/lane), LDS tree-reduce.
__global__ __launch_bounds__(256, 2) void snn_gemv(
    const float* __restrict__ Wint, const float* __restrict__ Wff,
    const float* __restrict__ T, const float* __restrict__ FF,
    float* __restrict__ part)
{
    __shared__ float c_lds[ROWS * BB];           // 4 KB  [row][b]
    __shared__ float red[2 * 2 * BB * 64];       // 16 KB [buf][r=2b+c][lane]
    int y = blockIdx.y;
    const float* Wm; const float* OP; int i0, opstride;
    if (y < YINT) { Wm = Wint; OP = T;  i0 = y * ROWS;          opstride = NN;  }
    else          { Wm = Wff;  OP = FF; i0 = (y - YINT) * ROWS; opstride = NFF; }

    int t = threadIdx.x;
    #pragma unroll
    for (int k = 0; k < ROWS * BB / 256; ++k) {
        int e = k * 256 + t;
        int row = e >> 4, b = e & 15;
        c_lds[e] = OP[b * opstride + i0 + row];
    }
    __syncthreads();

    int w = t >> 6, l = t & 63;
    int j0 = blockIdx.x * JC + l * 2;
    float2 acc[BB];
    #pragma unroll
    for (int b = 0; b < BB; ++b) acc[b] = make_float2(0.f, 0.f);

    // this wave's 16 rows: issue ALL loads up front (16 outstanding / lane)
    const float* wp = Wm + (size_t)(i0 + w * WR) * NN + j0;
    float2 buf[WR];
    #pragma unroll
    for (int r = 0; r < WR; ++r) buf[r] = *(const float2*)(wp + (size_t)r * NN);

    #pragma unroll
    for (int r = 0; r < WR; ++r) {
        const float4* cb = (const float4*)&c_lds[(w * WR + r) * BB];
        float4 c0 = cb[0], c1 = cb[1], c2 = cb[2], c3 = cb[3];
        float2 wv = buf[r];
#define FMA2(b, cc) acc[b].x += (cc) * wv.x; acc[b].y += (cc) * wv.y;
        FMA2(0,  c0.x) FMA2(1,  c0.y) FMA2(2,  c0.z) FMA2(3,  c0.w)
        FMA2(4,  c1.x) FMA2(5,  c1.y) FMA2(6,  c1.z) FMA2(7,  c1.w)
        FMA2(8,  c2.x) FMA2(9,  c2.y) FMA2(10, c2.z) FMA2(11, c2.w)
        FMA2(12, c3.x) FMA2(13, c3.y) FMA2(14, c3.z) FMA2(15, c3.w)
#undef FMA2
    }

    // tree-reduce the 4 waves' partials: [r][lane] layout, conflict-free b32
    if (w >= 2) {
        float* rb = &red[(w - 2) * 2 * BB * 64];
        #pragma unroll
        for (int b = 0; b < BB; ++b) {
            rb[(2 * b) * 64 + l]     = acc[b].x;
            rb[(2 * b + 1) * 64 + l] = acc[b].y;
        }
    }
    __syncthreads();
    if (w < 2) {
        const float* rb = &red[w * 2 * BB * 64];
        #pragma unroll
        for (int b = 0; b < BB; ++b) {
            acc[b].x += rb[(2 * b) * 64 + l];
            acc[b].y += rb[(2 * b + 1) * 64 + l];
        }
    }
    __syncthreads();
    if (w == 1) {
        #pragma unroll
        for (int b = 0; b < BB; ++b) {
            red[(2 * b) * 64 + l]     = acc[b].x;
            red[(2 * b + 1) * 64 + l] = acc[b].y;
        }
    }
    __syncthreads();
    if (w == 0) {
        float* pp = part + (size_t)y * (BB * NN) + j0;
        #pragma unroll
        for (int b = 0; b < BB; ++b) {
            acc[b].x += red[(2 * b) * 64 + l];
            acc[b].y += red[(2 * b + 1) * 64 + l];
            *(float2*)(pp + (size_t)b * NN) = acc[b];
        }
    }
}

// ---------------- Kernel 3: reduce partials + finalize ----------------
__global__ __launch_bounds__(256) void snn_post(
    const float* __restrict__ V, const float* __restrict__ xpost,
    const float* __restrict__ part, const float* __restrict__ scal_part,
    const float* __restrict__ out_X, float* __restrict__ out_V)
{
    int idx = blockIdx.x * 256 + threadIdx.x;
    int b = idx >> 11;
    float c1 = 0.f, c2 = 0.f, c3 = 0.f, c4 = 0.f;
    #pragma unroll
    for (int k = 0; k < 8; ++k) {
        c1 += scal_part[(b * 8 + k) * 2];
        c2 += scal_part[(b * 8 + k) * 2 + 1];
    }
    #pragma unroll
    for (int k = 0; k < 2; ++k) {
        c3 += scal_part[(128 + b * 2 + k) * 2];
        c4 += scal_part[(128 + b * 2 + k) * 2 + 1];
    }
    float s = 0.f;
    #pragma unroll
    for (int yy = 0; yy < YTOT; ++yy) s += part[(size_t)yy * (BB * NN) + idx];
    float x = out_X[idx];
    float c = s + 0.01f * (c1 + c3) * x - 0.012f * (c2 + c4) * xpost[idx];
    out_V[idx] = 0.9f * V[idx] * (1.f - x) + c;
}

extern "C" void kernel_launch(void* const* d_in, const int* in_sizes, int n_in,
                              void* d_out, int out_size, void* d_ws, size_t ws_size,
                              hipStream_t stream) {
    const float* FF       = (const float*)d_in[0];
    const float* V        = (const float*)d_in[1];
    const float* th       = (const float*)d_in[2];
    const float* Xbuf     = (const float*)d_in[3];
    const float* stp      = (const float*)d_in[4];
    const float* xpre_int = (const float*)d_in[5];
    const float* xpost    = (const float*)d_in[6];
    const float* xpre_ff  = (const float*)d_in[7];
    const float* Wint     = (const float*)d_in[8];
    const float* Wff      = (const float*)d_in[9];
    float* out = (float*)d_out;
    float* ws  = (float*)d_ws;

    float* T    = ws;                               // 32768 floats
    float* part = ws + BB * NN;                     // 40 * 32768 floats
    float* sp   = ws + BB * NN + YTOT * BB * NN;    // 320 floats

    snn_pre<<<(BB * NN + BB * NFF) / 256, 256, 0, stream>>>(
        FF, V, th, Xbuf, stp, xpre_int, xpre_ff, out, T, sp);

    snn_gemv<<<dim3(NN / JC, YTOT), 256, 0, stream>>>(
        Wint, Wff, T, FF, part);

    snn_post<<<BB * NN / 256, 256, 0, stream>>>(
        V, xpost, part, sp, out, out + BB * NN);
}